// Round 1
// 514.233 us; speedup vs baseline: 1.6764x; 1.6764x over previous
//
#include <hip/hip_runtime.h>
#include <math.h>

// Problem constants
#define BB 256          // batch
#define CC 256          // channels
#define MN 196          // H*W
#define TRI 32896       // C*(C+1)/2

// All intermediate matrices are stored as split-f16 pairs packed in a u32:
//   low  ushort = f16(hi)  = f16(32*v)
//   high ushort = f16(lo)  = f16(32*v - hi)
// The x32 storage scale keeps lo parts out of the f16 denormal range; it is
// undone via the alpha/diag constants of the consuming GEMM.
#define MSC 32.0f
#define INV_MSC  (1.0f/32.0f)
#define INV_MSC2 (1.0f/1024.0f)

typedef _Float16 f16;
typedef f16   f16x8 __attribute__((ext_vector_type(8)));
typedef float f32x4 __attribute__((ext_vector_type(4)));
typedef unsigned u32x4 __attribute__((ext_vector_type(4)));

__device__ __forceinline__ unsigned pack_split(float v) {
    f16 h = (f16)v;
    f16 l = (f16)(v - (float)h);
    return (unsigned)__builtin_bit_cast(unsigned short, h) |
           ((unsigned)__builtin_bit_cast(unsigned short, l) << 16);
}
__device__ __forceinline__ float unpack_split(unsigned w) {
    f16 h = __builtin_bit_cast(f16, (unsigned short)(w & 0xffffu));
    f16 l = __builtin_bit_cast(f16, (unsigned short)(w >> 16));
    return (float)h + (float)l;
}
// swap hi/lo within each 32-bit pair: (h0,l0,h1,l1,...) -> (l0,h0,l1,h1,...)
__device__ __forceinline__ f16x8 swap_pairs(f16x8 v) {
    return __builtin_shufflevector(v, v, 1, 0, 3, 2, 5, 4, 7, 6);
}
// async global->LDS, 16B per lane, LDS dest = uniform base + lane*16
__device__ __forceinline__ void gload_lds16(const unsigned* g, const f16* l) {
    __builtin_amdgcn_global_load_lds(
        (__attribute__((address_space(1))) void*)(size_t)g,
        (__attribute__((address_space(3))) void*)(unsigned)(size_t)l,
        16, 0, 0);
}

// ---------------------------------------------------------------------------
// Per-row mean AND per-row variance (one wave per (b,c) row of 196 floats).
// trace(cov) = sum_c var[c], so normA never needs the cov matrix.
// ---------------------------------------------------------------------------
__global__ __launch_bounds__(256) void meanvar_kernel(const float* __restrict__ x,
                                                      float* __restrict__ mu,
                                                      float* __restrict__ vr) {
    int wave = (blockIdx.x * 256 + threadIdx.x) >> 6;   // 0 .. B*C-1
    int lane = threadIdx.x & 63;
    const float* row = x + (size_t)wave * MN;
    float a0 = row[lane], a1 = row[lane + 64], a2 = row[lane + 128];
    float a3 = (lane < MN - 192) ? row[lane + 192] : 0.0f;
    float s = a0 + a1 + a2 + a3;
    float q = a0 * a0 + a1 * a1 + a2 * a2 + a3 * a3;
    #pragma unroll
    for (int off = 32; off > 0; off >>= 1) {
        s += __shfl_down(s, off, 64);
        q += __shfl_down(q, off, 64);
    }
    if (lane == 0) {
        float m = s * (1.0f / MN);
        mu[wave] = m;
        vr[wave] = q * (1.0f / MN) - m * m;
    }
}

// normA[b] = sum_c vr[b,c];  inv = 1/n, snorm = sqrt(n), invs = 1/sqrt(n)
__global__ __launch_bounds__(256) void norm_kernel(const float* __restrict__ vr,
                                                   float* __restrict__ inv,
                                                   float* __restrict__ snorm,
                                                   float* __restrict__ invs) {
    __shared__ float red[256];
    int b = blockIdx.x, i = threadIdx.x;
    red[i] = vr[b * CC + i];
    __syncthreads();
    for (int s = 128; s > 0; s >>= 1) {
        if (i < s) red[i] += red[i + s];
        __syncthreads();
    }
    if (i == 0) {
        float n = red[0];
        inv[b] = 1.0f / n;
        float sq = sqrtf(n);
        snorm[b] = sq;
        invs[b] = 1.0f / sq;
    }
}

// ---------------------------------------------------------------------------
// Covariance (VALU fp32, unchanged compute): epilogue now writes
// A = MSC * cov/normA directly in split-f16 form. Mirror keeps A EXACTLY
// symmetric so GEMMs may stage "columns" as rows.
// ---------------------------------------------------------------------------
__global__ __launch_bounds__(256) void cov_kernel(const float* __restrict__ x,
                                                  const float* __restrict__ mu,
                                                  const float* __restrict__ inv,
                                                  unsigned* __restrict__ Aout, int b0) {
    __shared__ __align__(16) float As[49][132];
    __shared__ __align__(16) float Bs[49][132];
    const int bl = blockIdx.x / 3;          // local batch (slot index)
    const int t  = blockIdx.x - 3 * bl;
    const int bg = b0 + bl;                 // global batch
    const int ti = (t == 2) ? 1 : 0;
    const int tj = (t == 0) ? 0 : 1;
    const int tid = threadIdx.x;
    const int tx = tid & 15, ty = tid >> 4;
    const float* xa = x + (size_t)bg * CC * MN + (size_t)ti * 128 * MN;
    const float* xb = x + (size_t)bg * CC * MN + (size_t)tj * 128 * MN;

    float acc[8][8];
    #pragma unroll
    for (int i = 0; i < 8; ++i)
        #pragma unroll
        for (int j = 0; j < 8; ++j) acc[i][j] = 0.0f;

    #pragma unroll 1
    for (int chunk = 0; chunk < 4; ++chunk) {
        const int m0 = chunk * 49;
        __syncthreads();
        #pragma unroll 5
        for (int it = 0; it < 25; ++it) {
            int f = tid + 256 * it;
            if (f < 128 * 49) {
                int r = f / 49;
                int m = f - r * 49;
                As[m][r] = xa[(size_t)r * MN + m0 + m];
                Bs[m][r] = xb[(size_t)r * MN + m0 + m];
            }
        }
        __syncthreads();
        #pragma unroll 7
        for (int m = 0; m < 49; ++m) {
            float4 a0 = *(const float4*)&As[m][4 * ty];
            float4 a1 = *(const float4*)&As[m][64 + 4 * ty];
            float4 b0v = *(const float4*)&Bs[m][4 * tx];
            float4 b1v = *(const float4*)&Bs[m][64 + 4 * tx];
            float av[8] = {a0.x, a0.y, a0.z, a0.w, a1.x, a1.y, a1.z, a1.w};
            float bv[8] = {b0v.x, b0v.y, b0v.z, b0v.w, b1v.x, b1v.y, b1v.z, b1v.w};
            #pragma unroll
            for (int i = 0; i < 8; ++i)
                #pragma unroll
                for (int j = 0; j < 8; ++j)
                    acc[i][j] = fmaf(av[i], bv[j], acc[i][j]);
        }
    }

    int rl[8], cl[8];
    #pragma unroll
    for (int i = 0; i < 4; ++i) {
        rl[i] = 4 * ty + i; rl[i + 4] = 64 + 4 * ty + i;
        cl[i] = 4 * tx + i; cl[i + 4] = 64 + 4 * tx + i;
    }
    const float* mub = mu + bg * CC;
    float mur[8], muc[8];
    #pragma unroll
    for (int i = 0; i < 8; ++i) {
        mur[i] = mub[ti * 128 + rl[i]];
        muc[i] = mub[tj * 128 + cl[i]];
    }
    const float iv = inv[bg] * MSC;
    float vals[8][8];
    #pragma unroll
    for (int i = 0; i < 8; ++i)
        #pragma unroll
        for (int j = 0; j < 8; ++j)
            vals[i][j] = (acc[i][j] * (1.0f / MN) - mur[i] * muc[j]) * iv;

    unsigned* Ab = Aout + (size_t)bl * CC * CC;
    #pragma unroll
    for (int i = 0; i < 8; ++i) {
        int gi = ti * 128 + rl[i];
        u32x4 lo = {pack_split(vals[i][0]), pack_split(vals[i][1]),
                    pack_split(vals[i][2]), pack_split(vals[i][3])};
        u32x4 hi = {pack_split(vals[i][4]), pack_split(vals[i][5]),
                    pack_split(vals[i][6]), pack_split(vals[i][7])};
        *(u32x4*)&Ab[(size_t)gi * CC + tj * 128 + 4 * tx] = lo;
        *(u32x4*)&Ab[(size_t)gi * CC + tj * 128 + 64 + 4 * tx] = hi;
    }
    if (ti != tj) {
        #pragma unroll
        for (int j = 0; j < 8; ++j) {
            int gj = tj * 128 + cl[j];
            u32x4 lo = {pack_split(vals[0][j]), pack_split(vals[1][j]),
                        pack_split(vals[2][j]), pack_split(vals[3][j])};
            u32x4 hi = {pack_split(vals[4][j]), pack_split(vals[5][j]),
                        pack_split(vals[6][j]), pack_split(vals[7][j])};
            *(u32x4*)&Ab[(size_t)gj * CC + ti * 128 + 4 * ty] = lo;
            *(u32x4*)&Ab[(size_t)gj * CC + ti * 128 + 64 + 4 * ty] = hi;
        }
    }
}

// ---------------------------------------------------------------------------
// MFMA NS-GEMM on split-f16 matrices.
//   stored C = al*acc + be*E + diag (al,be optionally * Sg[bg]); acc = A@B in
//   the *stored* scale (MSC^2), the host folds MSC corrections into al/diag.
// 2 MFMA passes per K-chunk over {hi,lo}-interleaved data:
//   pass1: A^ x B^        = sum(hh + ll)
//   pass2: A^ x swap(B^)  = sum(hl + lh)        -> full ~22-bit products.
// 128x128 tile, 4 waves (2x2), 64x64 per wave, mfma_f32_16x16x32_f16.
// Staging: global_load_lds w=16, linear LDS, source slot pre-XOR-swizzled
// (slot ^= (row>>1)&3) so ds_read_b128 frag reads spread across bank groups.
// ---------------------------------------------------------------------------
template <int FINAL>
__global__ __launch_bounds__(256) void ns_gemm_mfma(const unsigned* __restrict__ Ag,
                                                    const unsigned* __restrict__ Bg,
                                                    const unsigned* __restrict__ Eg,
                                                    void* __restrict__ Cg,
                                                    const float alpha0, const float beta0,
                                                    const float diag_add,
                                                    const float* __restrict__ Sg, int b0) {
    __shared__ __align__(16) f16 As[4096];   // 128 rows x 32 f16 (8 KiB)
    __shared__ __align__(16) f16 Bs[4096];
    const int bl = blockIdx.x / 3;
    const int t  = blockIdx.x - 3 * bl;
    const int bg = b0 + bl;
    const int ti = (t == 2) ? 1 : 0;
    const int tj = (t == 0) ? 0 : 1;
    const int tid  = threadIdx.x;
    const int lane = tid & 63;
    const int wid  = tid >> 6;
    const int wrow = wid >> 1, wcol = wid & 1;

    const unsigned* Abase = Ag + (size_t)bl * CC * CC + (size_t)(ti * 128) * CC;
    const unsigned* Bbase = Bg + (size_t)bl * CC * CC + (size_t)(tj * 128) * CC;

    // staging roles: wave0/1 -> A rows 0-63/64-127, wave2/3 -> B rows 0-63/64-127
    const unsigned* gsrc = ((wid < 2) ? Abase : Bbase) + (size_t)((wid & 1) * 64) * CC;
    f16* ldst = ((wid < 2) ? As : Bs) + (wid & 1) * 2048;
    const int srow  = lane >> 2;                       // 0..15
    const int sslot = (lane & 3) ^ ((lane >> 3) & 3);  // pre-swizzled source slot
    const unsigned* gsl = gsrc + (size_t)srow * CC + sslot * 4;

    // frag read byte offsets (swizzled)
    int aoff[4], boff[4];
    #pragma unroll
    for (int ib = 0; ib < 4; ++ib) {
        int ra = wrow * 64 + ib * 16 + (lane & 15);
        aoff[ib] = ra * 64 + ((((lane >> 4) ^ (ra >> 1)) & 3) << 4);
        int rb = wcol * 64 + ib * 16 + (lane & 15);
        boff[ib] = rb * 64 + ((((lane >> 4) ^ (rb >> 1)) & 3) << 4);
    }

    f32x4 acc[4][4];
    #pragma unroll
    for (int i = 0; i < 4; ++i)
        #pragma unroll
        for (int j = 0; j < 4; ++j) acc[i][j] = 0.0f;

    #pragma unroll 1
    for (int ks = 0; ks < 16; ++ks) {
        const int k0 = ks * 16;                  // u32 elements (= original k)
        __syncthreads();                         // previous-step reads done
        #pragma unroll
        for (int q = 0; q < 4; ++q)
            gload_lds16(gsl + (size_t)(q * 16) * CC + k0, ldst + q * 512);
        __syncthreads();                         // drains vmcnt -> tiles ready

        f16x8 av[4], bv[4], bw[4];
        #pragma unroll
        for (int ib = 0; ib < 4; ++ib)
            av[ib] = *(const f16x8*)((const char*)As + aoff[ib]);
        #pragma unroll
        for (int jb = 0; jb < 4; ++jb) {
            bv[jb] = *(const f16x8*)((const char*)Bs + boff[jb]);
            bw[jb] = swap_pairs(bv[jb]);
        }
        #pragma unroll
        for (int ib = 0; ib < 4; ++ib)
            #pragma unroll
            for (int jb = 0; jb < 4; ++jb) {
                acc[ib][jb] = __builtin_amdgcn_mfma_f32_16x16x32_f16(av[ib], bv[jb], acc[ib][jb], 0, 0, 0);
                acc[ib][jb] = __builtin_amdgcn_mfma_f32_16x16x32_f16(av[ib], bw[jb], acc[ib][jb], 0, 0, 0);
            }
    }

    // C/D frag: col = lane&15, row = (lane>>4)*4 + q  (guide-verified)
    const int gi0base = ti * 128 + wrow * 64 + ((lane >> 4) << 2);
    const int gjbase  = tj * 128 + wcol * 64 + (lane & 15);

    if (FINAL == 0) {
        float sc = (Sg != nullptr) ? Sg[bg] : 1.0f;
        float al = alpha0 * sc;
        float be = beta0 * sc;
        unsigned* Cb = (unsigned*)Cg + (size_t)bl * CC * CC;
        const unsigned* Eb = (Eg != nullptr) ? Eg + (size_t)bl * CC * CC : nullptr;
        #pragma unroll
        for (int ib = 0; ib < 4; ++ib) {
            #pragma unroll
            for (int jb = 0; jb < 4; ++jb) {
                int gi0 = gi0base + ib * 16;
                int gj  = gjbase + jb * 16;
                unsigned pk[4];
                #pragma unroll
                for (int q = 0; q < 4; ++q) {
                    int gi = gi0 + q;
                    float val = al * acc[ib][jb][q];
                    if (Eb) val += be * unpack_split(Eb[(size_t)gi * CC + gj]);
                    if (gi == gj) val += diag_add;
                    unsigned w = pack_split(val);
                    pk[q] = w;
                    Cb[(size_t)gi * CC + gj] = w;
                }
                if (ti != tj) {   // mirror -> exactly symmetric output
                    u32x4 m = {pk[0], pk[1], pk[2], pk[3]};
                    *(u32x4*)&Cb[(size_t)gj * CC + gi0] = m;
                }
            }
        }
    } else {
        float* ob = (float*)Cg + (size_t)bg * TRI;
        #pragma unroll
        for (int ib = 0; ib < 4; ++ib) {
            #pragma unroll
            for (int jb = 0; jb < 4; ++jb) {
                int gi0 = gi0base + ib * 16;
                int gj  = gjbase + jb * 16;
                #pragma unroll
                for (int q = 0; q < 4; ++q) {
                    int gi = gi0 + q;
                    if (gj >= gi)
                        ob[gi * CC - (gi * (gi - 1)) / 2 - gi + gj] = acc[ib][jb][q] * INV_MSC2;
                }
            }
        }
    }
}

// ---------------------------------------------------------------------------
// Schedule per chunk of g batches (4 split-matrix slots of 256KB/batch):
//   A  = MSC*cov/n                      (meanvar+norm once; cov writes split A)
//   Y1 = -0.5 A@A  + 1.5 A              -> s1
//   ZY1= 0.25 A@Y1 - 0.75 Y1 + 1.5 I    -> s2
//   Y2'= sqrt(n)*(Y1@ZY1)               -> s3
//   Z2'= (1/sqrt(n))*(-0.5 ZY1@A + 1.5 ZY1) -> s1
//   T  = -0.5 Z2'@Y2' + 1.5 I           -> s0
//   out= triu(Y2'@T)/MSC^2              -> d_out
// Scalar scratch lives in the TAIL of d_out (only overwritten by the very
// last FINAL gemm -> stream-ordered safe).
// ---------------------------------------------------------------------------
extern "C" void kernel_launch(void* const* d_in, const int* in_sizes, int n_in,
                              void* d_out, int out_size, void* d_ws, size_t ws_size,
                              hipStream_t stream) {
    const float* x = (const float*)d_in[0];
    float* out = (float*)d_out;
    unsigned* ws = (unsigned*)d_ws;

    const int SCR = 2 * BB * CC + 3 * BB;       // mu, vr, inv, snorm, invs
    float* mu    = out + (out_size - SCR);
    float* vr    = mu + BB * CC;
    float* inv   = vr + BB * CC;
    float* snorm = inv + BB;
    float* invs  = snorm + BB;

    size_t per_b = 4ull * CC * CC * sizeof(unsigned);   // 1 MiB per batch (4 slots)
    int gmax = (int)(ws_size / per_b);
    int g = 1;
    while (g * 2 <= gmax && g * 2 <= BB) g *= 2;

    size_t slotf = (size_t)g * CC * CC;
    unsigned* s0 = ws;
    unsigned* s1 = ws + slotf;
    unsigned* s2 = ws + 2 * slotf;
    unsigned* s3 = ws + 3 * slotf;

    meanvar_kernel<<<BB * CC / 4, 256, 0, stream>>>(x, mu, vr);
    norm_kernel<<<BB, 256, 0, stream>>>(vr, inv, snorm, invs);

    for (int b0 = 0; b0 < BB; b0 += g) {
        cov_kernel<<<g * 3, 256, 0, stream>>>(x, mu, inv, s0, b0);
        // Y1 = -0.5*(A@A) + 1.5*A
        ns_gemm_mfma<0><<<g * 3, 256, 0, stream>>>(s0, s0, s0, (void*)s1, -0.5f * INV_MSC, 1.5f, 0.0f, nullptr, b0);
        // ZY1 = 0.25*(A@Y1) - 0.75*Y1 + 1.5*I
        ns_gemm_mfma<0><<<g * 3, 256, 0, stream>>>(s0, s1, s1, (void*)s2, 0.25f * INV_MSC, -0.75f, 1.5f * MSC, nullptr, b0);
        // Y2' = snorm*(Y1@ZY1)
        ns_gemm_mfma<0><<<g * 3, 256, 0, stream>>>(s1, s2, nullptr, (void*)s3, INV_MSC, 0.0f, 0.0f, snorm, b0);
        // Z2' = invs*(-0.5*(ZY1@A) + 1.5*ZY1)
        ns_gemm_mfma<0><<<g * 3, 256, 0, stream>>>(s2, s0, s2, (void*)s1, -0.5f * INV_MSC, 1.5f, 0.0f, invs, b0);
        // T = -0.5*(Z2'@Y2') + 1.5*I
        ns_gemm_mfma<0><<<g * 3, 256, 0, stream>>>(s1, s3, nullptr, (void*)s0, -0.5f * INV_MSC, 0.0f, 1.5f * MSC, nullptr, b0);
        // out = triu(Y2'@T) / MSC^2
        ns_gemm_mfma<1><<<g * 3, 256, 0, stream>>>(s3, s0, nullptr, d_out, 0.0f, 0.0f, 0.0f, nullptr, b0);
    }
}

// Round 2
// 419.218 us; speedup vs baseline: 2.0563x; 1.2266x over previous
//
#include <hip/hip_runtime.h>
#include <math.h>

// Problem constants
#define BB 256          // batch
#define CC 256          // channels
#define MN 196          // H*W
#define TRI 32896       // C*(C+1)/2

// All intermediate matrices are stored as split-f16 pairs packed in a u32:
//   low  ushort = f16(hi)  = f16(32*v)
//   high ushort = f16(lo)  = f16(32*v - hi)
// The x32 storage scale keeps lo parts out of the f16 denormal range; it is
// undone via the alpha/diag constants of the consuming GEMM.
#define MSC 32.0f
#define INV_MSC  (1.0f/32.0f)
#define INV_MSC2 (1.0f/1024.0f)

typedef _Float16 f16;
typedef f16   f16x8 __attribute__((ext_vector_type(8)));
typedef float f32x4 __attribute__((ext_vector_type(4)));
typedef unsigned u32x4 __attribute__((ext_vector_type(4)));

__device__ __forceinline__ unsigned pack_split(float v) {
    f16 h = (f16)v;
    f16 l = (f16)(v - (float)h);
    return (unsigned)__builtin_bit_cast(unsigned short, h) |
           ((unsigned)__builtin_bit_cast(unsigned short, l) << 16);
}
__device__ __forceinline__ float unpack_split(unsigned w) {
    f16 h = __builtin_bit_cast(f16, (unsigned short)(w & 0xffffu));
    f16 l = __builtin_bit_cast(f16, (unsigned short)(w >> 16));
    return (float)h + (float)l;
}
// swap hi/lo within each 32-bit pair: (h0,l0,h1,l1,...) -> (l0,h0,l1,h1,...)
__device__ __forceinline__ f16x8 swap_pairs(f16x8 v) {
    return __builtin_shufflevector(v, v, 1, 0, 3, 2, 5, 4, 7, 6);
}
// async global->LDS, 16B per lane, LDS dest = wave-uniform base + lane*16
__device__ __forceinline__ void gload_lds16(const unsigned* g, const f16* l) {
    __builtin_amdgcn_global_load_lds(
        (__attribute__((address_space(1))) void*)(size_t)g,
        (__attribute__((address_space(3))) void*)(unsigned)(size_t)l,
        16, 0, 0);
}

// ---------------------------------------------------------------------------
// Per-row mean AND per-row variance (one wave per (b,c) row of 196 floats).
// trace(cov) = sum_c var[c], so normA never needs the cov matrix.
// ---------------------------------------------------------------------------
__global__ __launch_bounds__(256) void meanvar_kernel(const float* __restrict__ x,
                                                      float* __restrict__ mu,
                                                      float* __restrict__ vr) {
    int wave = (blockIdx.x * 256 + threadIdx.x) >> 6;   // 0 .. B*C-1
    int lane = threadIdx.x & 63;
    const float* row = x + (size_t)wave * MN;
    float a0 = row[lane], a1 = row[lane + 64], a2 = row[lane + 128];
    float a3 = (lane < MN - 192) ? row[lane + 192] : 0.0f;
    float s = a0 + a1 + a2 + a3;
    float q = a0 * a0 + a1 * a1 + a2 * a2 + a3 * a3;
    #pragma unroll
    for (int off = 32; off > 0; off >>= 1) {
        s += __shfl_down(s, off, 64);
        q += __shfl_down(q, off, 64);
    }
    if (lane == 0) {
        float m = s * (1.0f / MN);
        mu[wave] = m;
        vr[wave] = q * (1.0f / MN) - m * m;
    }
}

// normA[b] = sum_c vr[b,c];  inv = 1/n, snorm = sqrt(n), invs = 1/sqrt(n)
__global__ __launch_bounds__(256) void norm_kernel(const float* __restrict__ vr,
                                                   float* __restrict__ inv,
                                                   float* __restrict__ snorm,
                                                   float* __restrict__ invs) {
    __shared__ float red[256];
    int b = blockIdx.x, i = threadIdx.x;
    red[i] = vr[b * CC + i];
    __syncthreads();
    for (int s = 128; s > 0; s >>= 1) {
        if (i < s) red[i] += red[i + s];
        __syncthreads();
    }
    if (i == 0) {
        float n = red[0];
        inv[b] = 1.0f / n;
        float sq = sqrtf(n);
        snorm[b] = sq;
        invs[b] = 1.0f / sq;
    }
}

// ---------------------------------------------------------------------------
// xs = split-f16(MSC * (x - mu)), K padded 196 -> 208 u32 with zeros.
// One wave per (b,c) row. xs is [bl][256][208] u32, lives in slot s1.
// ---------------------------------------------------------------------------
__global__ __launch_bounds__(256) void xsplit_kernel(const float* __restrict__ x,
                                                     const float* __restrict__ mu,
                                                     unsigned* __restrict__ xs, int b0) {
    int wave = (blockIdx.x * 256 + threadIdx.x) >> 6;   // bl*256 + c
    int lane = threadIdx.x & 63;
    int bl = wave >> 8;
    int c  = wave & 255;
    int bg = b0 + bl;
    const float* row = x + ((size_t)bg * CC + c) * MN;
    float m = mu[bg * CC + c];
    unsigned* orow = xs + (size_t)bl * (CC * 208) + (size_t)c * 208;
    orow[lane]       = pack_split(MSC * (row[lane] - m));
    orow[lane + 64]  = pack_split(MSC * (row[lane + 64] - m));
    orow[lane + 128] = pack_split(MSC * (row[lane + 128] - m));
    if (lane < 4)       orow[lane + 192] = pack_split(MSC * (row[lane + 192] - m));
    else if (lane < 16) orow[lane + 192] = 0u;
}

// ---------------------------------------------------------------------------
// Unified split-f16 MFMA GEMM. 128x128 tile, 512 threads (8 waves, 2x4),
// each wave 64x32 output, mfma_f32_16x16x32_f16, two passes (bv / swap(bv))
// per K-chunk -> exact product of split values, fp32 accumulate.
// 2-phase pipeline: issue next chunk's global_load_lds BEFORE compute, one
// barrier per chunk (T3-minimum; barrier's implicit vmcnt(0) drains stage).
// MODE 0: NS update  C = al*acc + be*E + diag (al,be opt. * Sg[bg]); mirror.
// MODE 1: FINAL      out(triu) = acc * INV_MSC2 (fp32).
// MODE 2: COV        same epilogue as 0, but A=B=xs (LDK=208, 13 chunks).
// ---------------------------------------------------------------------------
template <int MODE>
__global__ __launch_bounds__(512) void gemm512(const unsigned* __restrict__ Ag,
                                               const unsigned* __restrict__ Bg,
                                               const unsigned* __restrict__ Eg,
                                               void* __restrict__ Cg,
                                               const float alpha0, const float beta0,
                                               const float diag_add,
                                               const float* __restrict__ Sg, int b0) {
    constexpr int    LDK = (MODE == 2) ? 208 : 256;          // u32 per row
    constexpr int    KCH = (MODE == 2) ? 13  : 16;           // 16-u32 chunks
    constexpr size_t BST = (MODE == 2) ? (size_t)CC * 208 : (size_t)CC * CC;
    __shared__ __align__(16) f16 As[2][4096];   // [buf][128 rows x 32 f16]
    __shared__ __align__(16) f16 Bs[2][4096];
    const int bl = blockIdx.x / 3;
    const int t  = blockIdx.x - 3 * bl;
    const int bg = b0 + bl;
    const int ti = (t == 2) ? 1 : 0;
    const int tj = (t == 0) ? 0 : 1;
    const int tid  = threadIdx.x;
    const int lane = tid & 63;
    const int wid  = tid >> 6;
    const int wrow = wid >> 2, wcol = wid & 3;

    const unsigned* Abase = Ag + (size_t)bl * BST + (size_t)(ti * 128) * LDK;
    const unsigned* Bbase = Bg + (size_t)bl * BST + (size_t)(tj * 128) * LDK;

    // staging: waves 0-3 -> As, waves 4-7 -> Bs; per wave two 16-row blocks
    const int sw = wid & 3;
    const unsigned* gsrc = (wid < 4) ? Abase : Bbase;
    const int srow0 = sw * 32 + (lane >> 2);               // q=1 adds 16 rows
    const int sslot = (lane & 3) ^ ((lane >> 3) & 3);      // pre-swizzled slot
    const unsigned* gsl = gsrc + (size_t)srow0 * LDK + sslot * 4;
    f16* lbase = ((wid < 4) ? &As[0][0] : &Bs[0][0]) + sw * 1024;

    // frag read byte offsets within one buffer (swizzled)
    int aoff[4], boff[2];
    #pragma unroll
    for (int ib = 0; ib < 4; ++ib) {
        int ra = wrow * 64 + ib * 16 + (lane & 15);
        aoff[ib] = ra * 64 + ((((lane >> 4) ^ (ra >> 1)) & 3) << 4);
    }
    #pragma unroll
    for (int jb = 0; jb < 2; ++jb) {
        int rb = wcol * 32 + jb * 16 + (lane & 15);
        boff[jb] = rb * 64 + ((((lane >> 4) ^ (rb >> 1)) & 3) << 4);
    }

    f32x4 acc[4][2];
    #pragma unroll
    for (int i = 0; i < 4; ++i)
        #pragma unroll
        for (int j = 0; j < 2; ++j) acc[i][j] = 0.0f;

    auto STAGE = [&](int nb, int ks) {
        const unsigned* s = gsl + ks * 16;
        f16* d = lbase + nb * 4096;
        gload_lds16(s, d);
        gload_lds16(s + (size_t)16 * LDK, d + 512);
    };

    STAGE(0, 0);
    __syncthreads();
    #pragma unroll 2
    for (int ks = 0; ks < KCH; ++ks) {
        const int nb = ks & 1;
        if (ks + 1 < KCH) STAGE(nb ^ 1, ks + 1);
        const char* Ab8 = (const char*)As + nb * 8192;
        const char* Bb8 = (const char*)Bs + nb * 8192;
        f16x8 av[4], bv[2], bw[2];
        #pragma unroll
        for (int ib = 0; ib < 4; ++ib)
            av[ib] = *(const f16x8*)(Ab8 + aoff[ib]);
        #pragma unroll
        for (int jb = 0; jb < 2; ++jb) {
            bv[jb] = *(const f16x8*)(Bb8 + boff[jb]);
            bw[jb] = swap_pairs(bv[jb]);
        }
        #pragma unroll
        for (int ib = 0; ib < 4; ++ib)
            #pragma unroll
            for (int jb = 0; jb < 2; ++jb) {
                acc[ib][jb] = __builtin_amdgcn_mfma_f32_16x16x32_f16(av[ib], bv[jb], acc[ib][jb], 0, 0, 0);
                acc[ib][jb] = __builtin_amdgcn_mfma_f32_16x16x32_f16(av[ib], bw[jb], acc[ib][jb], 0, 0, 0);
            }
        __syncthreads();   // drains vmcnt (stage landed) + all reads of nb done
    }

    // C/D frag: col = lane&15, row = (lane>>4)*4 + q  (harness-verified)
    const int gi0base = ti * 128 + wrow * 64 + ((lane >> 4) << 2);
    const int gjbase  = tj * 128 + wcol * 32 + (lane & 15);

    if (MODE != 1) {
        float sc = (Sg != nullptr) ? Sg[bg] : 1.0f;
        float al = alpha0 * sc;
        float be = beta0 * sc;
        unsigned* Cb = (unsigned*)Cg + (size_t)bl * CC * CC;
        const unsigned* Eb = (Eg != nullptr) ? Eg + (size_t)bl * CC * CC : nullptr;
        #pragma unroll
        for (int ib = 0; ib < 4; ++ib) {
            #pragma unroll
            for (int jb = 0; jb < 2; ++jb) {
                int gi0 = gi0base + ib * 16;
                int gj  = gjbase + jb * 16;
                unsigned pk[4];
                #pragma unroll
                for (int q = 0; q < 4; ++q) {
                    int gi = gi0 + q;
                    float val = al * acc[ib][jb][q];
                    if (Eb) val += be * unpack_split(Eb[(size_t)gi * CC + gj]);
                    if (gi == gj) val += diag_add;
                    unsigned w = pack_split(val);
                    pk[q] = w;
                    Cb[(size_t)gi * CC + gj] = w;
                }
                if (ti != tj) {   // mirror -> exactly symmetric output
                    u32x4 m = {pk[0], pk[1], pk[2], pk[3]};
                    *(u32x4*)&Cb[(size_t)gj * CC + gi0] = m;
                }
            }
        }
    } else {
        float* ob = (float*)Cg + (size_t)bg * TRI;
        #pragma unroll
        for (int ib = 0; ib < 4; ++ib) {
            #pragma unroll
            for (int jb = 0; jb < 2; ++jb) {
                int gi0 = gi0base + ib * 16;
                int gj  = gjbase + jb * 16;
                #pragma unroll
                for (int q = 0; q < 4; ++q) {
                    int gi = gi0 + q;
                    if (gj >= gi)
                        ((float*)Cg + (size_t)bg * TRI)[gi * CC - (gi * (gi - 1)) / 2 - gi + gj]
                            = acc[ib][jb][q] * INV_MSC2;
                }
                (void)ob;
            }
        }
    }
}

// ---------------------------------------------------------------------------
// Schedule per chunk of g batches (4 split-matrix slots of 256KB/batch):
//   xs = split(MSC*(x-mu))              -> s1 (xs fits: 53248 <= 65536 u32/b)
//   A  = MSC*cov/n = Gram(xs)*inv/(MSC*MN)   (MFMA, MODE 2) -> s0
//   Y1 = -0.5 A@A  + 1.5 A              -> s1   (overwrites dead xs)
//   ZY1= 0.25 A@Y1 - 0.75 Y1 + 1.5 I    -> s2
//   Y2'= sqrt(n)*(Y1@ZY1)               -> s3
//   Z2'= (1/sqrt(n))*(-0.5 ZY1@A + 1.5 ZY1) -> s1
//   T  = -0.5 Z2'@Y2' + 1.5 I           -> s0
//   out= triu(Y2'@T)/MSC^2              -> d_out
// Scalar scratch lives in the TAIL of d_out (only overwritten by the very
// last FINAL gemm -> stream-ordered safe).
// ---------------------------------------------------------------------------
extern "C" void kernel_launch(void* const* d_in, const int* in_sizes, int n_in,
                              void* d_out, int out_size, void* d_ws, size_t ws_size,
                              hipStream_t stream) {
    const float* x = (const float*)d_in[0];
    float* out = (float*)d_out;
    unsigned* ws = (unsigned*)d_ws;

    const int SCR = 2 * BB * CC + 3 * BB;       // mu, vr, inv, snorm, invs
    float* mu    = out + (out_size - SCR);
    float* vr    = mu + BB * CC;
    float* inv   = vr + BB * CC;
    float* snorm = inv + BB;
    float* invs  = snorm + BB;

    size_t per_b = 4ull * CC * CC * sizeof(unsigned);   // 1 MiB per batch (4 slots)
    int gmax = (int)(ws_size / per_b);
    int g = 1;
    while (g * 2 <= gmax && g * 2 <= BB) g *= 2;

    size_t slotf = (size_t)g * CC * CC;
    unsigned* s0 = ws;
    unsigned* s1 = ws + slotf;
    unsigned* s2 = ws + 2 * slotf;
    unsigned* s3 = ws + 3 * slotf;

    meanvar_kernel<<<BB * CC / 4, 256, 0, stream>>>(x, mu, vr);
    norm_kernel<<<BB, 256, 0, stream>>>(vr, inv, snorm, invs);

    for (int b0 = 0; b0 < BB; b0 += g) {
        // xs (split centered x) into s1
        xsplit_kernel<<<g * 64, 256, 0, stream>>>(x, mu, s1, b0);
        // A = Gram(xs) * inv / (MSC*MN)   (stored MSC-scaled)
        gemm512<2><<<g * 3, 512, 0, stream>>>(s1, s1, nullptr, (void*)s0,
                                              1.0f / (MSC * MN), 0.0f, 0.0f, inv, b0);
        // Y1 = -0.5*(A@A) + 1.5*A
        gemm512<0><<<g * 3, 512, 0, stream>>>(s0, s0, s0, (void*)s1, -0.5f * INV_MSC, 1.5f, 0.0f, nullptr, b0);
        // ZY1 = 0.25*(A@Y1) - 0.75*Y1 + 1.5*I
        gemm512<0><<<g * 3, 512, 0, stream>>>(s0, s1, s1, (void*)s2, 0.25f * INV_MSC, -0.75f, 1.5f * MSC, nullptr, b0);
        // Y2' = snorm*(Y1@ZY1)
        gemm512<0><<<g * 3, 512, 0, stream>>>(s1, s2, nullptr, (void*)s3, INV_MSC, 0.0f, 0.0f, snorm, b0);
        // Z2' = invs*(-0.5*(ZY1@A) + 1.5*ZY1)
        gemm512<0><<<g * 3, 512, 0, stream>>>(s2, s0, s2, (void*)s1, -0.5f * INV_MSC, 1.5f, 0.0f, invs, b0);
        // T = -0.5*(Z2'@Y2') + 1.5*I
        gemm512<0><<<g * 3, 512, 0, stream>>>(s1, s3, nullptr, (void*)s0, -0.5f * INV_MSC, 0.0f, 1.5f * MSC, nullptr, b0);
        // out = triu(Y2'@T) / MSC^2
        gemm512<1><<<g * 3, 512, 0, stream>>>(s3, s0, nullptr, d_out, 0.0f, 0.0f, 0.0f, nullptr, b0);
    }
}